// Round 1
// baseline (1808.675 us; speedup 1.0000x reference)
//
#include <hip/hip_runtime.h>

#define HH 128
#define TT 1024
#define NFUT 64
#define MB 2            // real batch rows per workgroup
#define NBLK 256        // 512 / MB

typedef _Float16 half8 __attribute__((ext_vector_type(8)));
typedef float floatx4 __attribute__((ext_vector_type(4)));

#define MFMA16(a, b, c) __builtin_amdgcn_mfma_f32_16x16x32_f16((a), (b), (c), 0, 0, 0)

__device__ __forceinline__ float sigm(float v) {
  // 1/(1+e^-v) ; e^-v overflow -> inf -> rcp -> 0 (correct limit)
  return __builtin_amdgcn_rcpf(1.0f + __builtin_amdgcn_exp2f(v * -1.442695040888963f));
}
__device__ __forceinline__ float tanh_f(float v) {
  float a = __builtin_fabsf(v);
  float e = __builtin_amdgcn_exp2f(a * -2.885390081777927f);  // e^(-2|v|) in (0,1]
  float r = (1.0f - e) * __builtin_amdgcn_rcpf(1.0f + e);
  return __builtin_copysignf(r, v);
}

__device__ __forceinline__ half8 ldw8(const float* __restrict__ p) {
  half8 r;
#pragma unroll
  for (int i = 0; i < 8; ++i) r[i] = (_Float16)p[i];
  return r;
}

// Persistent 2-layer LSTM. Grid 256 x 512 threads. Each WG owns MB=2 batch rows.
// Wave w (0..7) owns hidden units j in [w*16, w*16+16) of BOTH cells:
//  - holds W_hh1/W_ih2/W_hh2 rows {q*128+j} as f16 MFMA B-fragments in VGPRs (192 VGPRs)
//  - h vectors roundtrip through LDS stored in A-fragment order:
//      element (b,k) at  kf*512 + (b + 16*((k>>3)&3))*8 + (k&7),  kf = k>>5
//    so reads are ds_read_b128 at lane*16 + kf*1024 : conflict-free.
__global__ __launch_bounds__(512, 2) void lstm_kernel(
    const float* __restrict__ x,
    const float* __restrict__ W_ih1, const float* __restrict__ b_ih1,
    const float* __restrict__ W_hh1, const float* __restrict__ b_hh1,
    const float* __restrict__ W_ih2, const float* __restrict__ b_ih2,
    const float* __restrict__ W_hh2, const float* __restrict__ b_hh2,
    const float* __restrict__ W_out, const float* __restrict__ b_out,
    float* __restrict__ out)
{
  __shared__ __align__(16) _Float16 xs[TT * 16];     // [t][b] f16, b>=MB zeroed (32KB)
  __shared__ __align__(16) _Float16 h1b[2 * 2048];   // double-buffered h1, frag order
  __shared__ __align__(16) _Float16 h2b[2 * 2048];   // double-buffered h2, frag order
  __shared__ float oscr[8 * 16];                     // out-projection partials per wave
  __shared__ float xfut[16];                         // previous output (future phase)

  const int tid = (int)threadIdx.x;
  const int lane = tid & 63;
  const int w = tid >> 6;
  const int jl = lane & 15;
  const int rg = lane >> 4;
  const int j = (w << 4) + jl;            // hidden unit 0..127 this lane finalizes
  const int b0g = (int)blockIdx.x * MB;   // global batch base

  // ---- preload x -> LDS as f16 [t][16] (coalesced over t) ----
  for (int idx = tid; idx < TT * 16; idx += 512) {
    int b = idx >> 10;
    int t = idx & (TT - 1);
    float v = (b < MB) ? x[(b0g + b) * TT + t] : 0.0f;
    xs[t * 16 + b] = (_Float16)v;
  }
  for (int i = tid; i < 2 * 2048; i += 512) {
    h1b[i] = (_Float16)0.0f;
    h2b[i] = (_Float16)0.0f;
  }

  // ---- weights -> VGPR B-fragments (f16) ----
  // B-frag for 16x16x32: lane holds B[k=(lane>>4)*8+i][n=lane&15]; B[k][n] = W[row0+n][k]
  half8 fr1[4][4], f2i[4][4], f2h[4][4];
#pragma unroll
  for (int q = 0; q < 4; ++q) {
#pragma unroll
    for (int kf = 0; kf < 4; ++kf) {
      int row = q * HH + j;
      int kb = kf * 32 + rg * 8;
      fr1[q][kf] = ldw8(W_hh1 + row * HH + kb);
      f2i[q][kf] = ldw8(W_ih2 + row * HH + kb);
      f2h[q][kf] = ldw8(W_hh2 + row * HH + kb);
    }
  }
  float bias1[4], bias2[4], wi1[4];
#pragma unroll
  for (int q = 0; q < 4; ++q) {
    bias1[q] = b_ih1[q * HH + j] + b_hh1[q * HH + j];
    bias2[q] = b_ih2[q * HH + j] + b_hh2[q * HH + j];
    wi1[q] = W_ih1[q * HH + j];
  }
  const float wo = W_out[j];
  const float bo = b_out[0];

  floatx4 c1 = {0.0f, 0.0f, 0.0f, 0.0f};
  floatx4 c2 = {0.0f, 0.0f, 0.0f, 0.0f};

  __syncthreads();

  const int aoff = lane * 8;  // A-frag read offset (elements)
  // write index constant: frag (j>>5), lane-group ((j>>3)&3), byte elem (j&7)
  const int wconst = ((j >> 5) << 9) + (((j >> 3) & 3) << 7) + (j & 7);

  for (int t = 0; t < TT + NFUT - 1; ++t) {
    const int cur = (t & 1);
    const _Float16* h1c = h1b + cur * 2048;
    _Float16* h1n = h1b + (cur ^ 1) * 2048;
    const _Float16* h2c = h2b + cur * 2048;
    _Float16* h2n = h2b + (cur ^ 1) * 2048;

    // ---- P1: cell1 gates = h1(t-1) @ W_hh1^T ----
    floatx4 a0 = {0,0,0,0}, a1 = {0,0,0,0}, a2 = {0,0,0,0}, a3 = {0,0,0,0};
#pragma unroll
    for (int kf = 0; kf < 4; ++kf) {
      half8 av = *(const half8*)(h1c + (kf << 9) + aoff);
      a0 = MFMA16(av, fr1[0][kf], a0);
      a1 = MFMA16(av, fr1[1][kf], a1);
      a2 = MFMA16(av, fr1[2][kf], a2);
      a3 = MFMA16(av, fr1[3][kf], a3);
    }

    // ---- P2: finalize cell1 -> h1(t) (only real batch rows; others execz-skip) ----
    float xv[4];
    if (t < TT) {
#pragma unroll
      for (int r = 0; r < 4; ++r) xv[r] = (float)xs[t * 16 + rg * 4 + r];
    } else {
#pragma unroll
      for (int r = 0; r < 4; ++r) xv[r] = xfut[rg * 4 + r];
    }
#pragma unroll
    for (int r = 0; r < 4; ++r) {
      if (rg * 4 + r < MB) {
        float gi = a0[r] + xv[r] * wi1[0] + bias1[0];
        float gf = a1[r] + xv[r] * wi1[1] + bias1[1];
        float gg = a2[r] + xv[r] * wi1[2] + bias1[2];
        float go = a3[r] + xv[r] * wi1[3] + bias1[3];
        float cc = sigm(gf) * c1[r] + sigm(gi) * tanh_f(gg);
        c1[r] = cc;
        float hh = sigm(go) * tanh_f(cc);
        h1n[wconst + ((rg * 4 + r) << 3)] = (_Float16)hh;
      }
    }
    __syncthreads();

    // ---- P3: cell2 gates = h2(t-1) @ W_hh2^T + h1(t) @ W_ih2^T ----
    floatx4 g0 = {0,0,0,0}, g1 = {0,0,0,0}, g2 = {0,0,0,0}, g3 = {0,0,0,0};
#pragma unroll
    for (int kf = 0; kf < 4; ++kf) {
      half8 av = *(const half8*)(h2c + (kf << 9) + aoff);
      g0 = MFMA16(av, f2h[0][kf], g0);
      g1 = MFMA16(av, f2h[1][kf], g1);
      g2 = MFMA16(av, f2h[2][kf], g2);
      g3 = MFMA16(av, f2h[3][kf], g3);
    }
#pragma unroll
    for (int kf = 0; kf < 4; ++kf) {
      half8 av = *(const half8*)(h1n + (kf << 9) + aoff);
      g0 = MFMA16(av, f2i[0][kf], g0);
      g1 = MFMA16(av, f2i[1][kf], g1);
      g2 = MFMA16(av, f2i[2][kf], g2);
      g3 = MFMA16(av, f2i[3][kf], g3);
    }

    // ---- P4: finalize cell2 -> h2(t), optional output projection ----
    float hvr[4] = {0.0f, 0.0f, 0.0f, 0.0f};
#pragma unroll
    for (int r = 0; r < 4; ++r) {
      if (rg * 4 + r < MB) {
        float gi = g0[r] + bias2[0];
        float gf = g1[r] + bias2[1];
        float gg = g2[r] + bias2[2];
        float go = g3[r] + bias2[3];
        float cc = sigm(gf) * c2[r] + sigm(gi) * tanh_f(gg);
        c2[r] = cc;
        float hh = sigm(go) * tanh_f(cc);
        h2n[wconst + ((rg * 4 + r) << 3)] = (_Float16)hh;
        hvr[r] = hh;
      }
    }

    if (t >= TT - 1) {
      // out[b] = sum_j h2[b][j]*W_out[j] + b_out ; reduce over 16 lanes per group
      if (rg == 0) {
#pragma unroll
        for (int r = 0; r < MB; ++r) {
          float p = hvr[r] * wo;
          p += __shfl_xor(p, 1);
          p += __shfl_xor(p, 2);
          p += __shfl_xor(p, 4);
          p += __shfl_xor(p, 8);
          if (jl == 0) oscr[w * 16 + r] = p;
        }
      }
      __syncthreads();
      if (tid < MB) {
        float s = bo;
#pragma unroll
        for (int ww = 0; ww < 8; ++ww) s += oscr[ww * 16 + tid];
        out[(b0g + tid) * NFUT + (t - (TT - 1))] = s;
        xfut[tid] = s;
      }
    }
    __syncthreads();
  }
}

extern "C" void kernel_launch(void* const* d_in, const int* in_sizes, int n_in,
                              void* d_out, int out_size, void* d_ws, size_t ws_size,
                              hipStream_t stream) {
  const float* x     = (const float*)d_in[0];
  const float* W_ih1 = (const float*)d_in[1];
  const float* b_ih1 = (const float*)d_in[2];
  const float* W_hh1 = (const float*)d_in[3];
  const float* b_hh1 = (const float*)d_in[4];
  const float* W_ih2 = (const float*)d_in[5];
  const float* b_ih2 = (const float*)d_in[6];
  const float* W_hh2 = (const float*)d_in[7];
  const float* b_hh2 = (const float*)d_in[8];
  const float* W_out = (const float*)d_in[9];
  const float* b_out = (const float*)d_in[10];
  (void)in_sizes; (void)n_in; (void)out_size; (void)d_ws; (void)ws_size;

  lstm_kernel<<<dim3(NBLK), dim3(512), 0, stream>>>(
      x, W_ih1, b_ih1, W_hh1, b_hh1, W_ih2, b_ih2, W_hh2, b_hh2, W_out, b_out,
      (float*)d_out);
}